// Round 7
// baseline (595.791 us; speedup 1.0000x reference)
//
#include <hip/hip_runtime.h>
#include <hip/hip_bf16.h>

// RGCN: 2-layer relational GCN + L2 normalize.
// R6 hybrid: L1 aggregate-first (k_agg1: 512-key bucket sort + R4-style gather
// of xb, 8 edges in flight); L2 transform-first (k_gemmT -> t2, k_final gathers
// 128B/edge + fused L2norm). KPB=512 keeps k_part writes coalesced.

typedef unsigned int uint;
typedef unsigned short ushort;
typedef __attribute__((ext_vector_type(8))) short short8;
typedef __attribute__((ext_vector_type(16))) float floatx16;

#define IN_CH  128
#define OUT_CH 64
#define SCAN_CHUNK 2048
#define EPB 8192          // edges per partition block
#define KPB 512           // keys per bucket (256 nodes x 2 rels)
#define MAXBK 400         // bucket counters (NBK=391)
#define SRCCAP 5120       // LDS edge capacity per bucket (mean 4096, +16 sigma)

__device__ __forceinline__ ushort f2bf(float f) {
    uint u = __float_as_uint(f);
    u += 0x7FFF + ((u >> 16) & 1);
    return (ushort)(u >> 16);
}
__device__ __forceinline__ float bflo(uint u) { return __uint_as_float(u << 16); }
__device__ __forceinline__ float bfhi(uint u) { return __uint_as_float(u & 0xFFFF0000u); }

// ---------------- radix partition: key = 2*dst + et, bucket = key>>9 -------

__global__ void k_count(const int* __restrict__ dst, const int* __restrict__ et,
                        int* __restrict__ cntblk, int E, int NBK, int NBLK) {
    __shared__ int cnt[MAXBK];
    int tid = threadIdx.x, blk = blockIdx.x;
    for (int b = tid; b < NBK; b += 256) cnt[b] = 0;
    __syncthreads();
    int base = blk * EPB;
#pragma unroll 4
    for (int i = 0; i < EPB / 256; i++) {
        int e = base + i * 256 + tid;
        if (e < E) {
            int key = 2 * dst[e] + et[e];
            atomicAdd(&cnt[key >> 9], 1);
        }
    }
    __syncthreads();
    for (int b = tid; b < NBK; b += 256) cntblk[b * NBLK + blk] = cnt[b];
}

__global__ void k_scan_a(const int* __restrict__ deg, int* __restrict__ offs,
                         int* __restrict__ bsums, int n) {
    __shared__ int sdata[256];
    int b = blockIdx.x, t = threadIdx.x;
    int base = b * SCAN_CHUNK + t * 8;
    int v[8];
    int sum = 0;
#pragma unroll
    for (int i = 0; i < 8; i++) {
        int idx = base + i;
        int x = (idx < n) ? deg[idx] : 0;
        v[i] = sum;
        sum += x;
    }
    sdata[t] = sum;
    __syncthreads();
    for (int ofs = 1; ofs < 256; ofs <<= 1) {
        int val = sdata[t];
        int add = (t >= ofs) ? sdata[t - ofs] : 0;
        __syncthreads();
        sdata[t] = val + add;
        __syncthreads();
    }
    int texcl = (t == 0) ? 0 : sdata[t - 1];
    if (t == 255) bsums[b] = sdata[255];
#pragma unroll
    for (int i = 0; i < 8; i++) {
        int idx = base + i;
        if (idx < n) offs[idx] = texcl + v[i];
    }
}

__global__ void k_scan_b(int* __restrict__ bsums, int* __restrict__ offs, int nb, int n) {
    if (blockIdx.x == 0 && threadIdx.x == 0) {
        int run = 0;
        for (int b = 0; b < nb; b++) {
            int t = bsums[b];
            bsums[b] = run;
            run += t;
        }
        offs[n] = run;
    }
}

__global__ void k_scan_c(int* __restrict__ offs, const int* __restrict__ bsums, int n) {
    int i = blockIdx.x * blockDim.x + threadIdx.x;
    if (i < n) offs[i] += bsums[i / SCAN_CHUNK];
}

__global__ void k_part(const int* __restrict__ src, const int* __restrict__ dst,
                       const int* __restrict__ et, const int* __restrict__ basebb,
                       uint2* __restrict__ stage, int E, int NBK, int NBLK) {
    __shared__ int cnt[MAXBK];
    __shared__ int basel[MAXBK];
    int tid = threadIdx.x, blk = blockIdx.x;
    for (int b = tid; b < NBK; b += 256) {
        cnt[b] = 0;
        basel[b] = basebb[b * NBLK + blk];
    }
    __syncthreads();
    int base = blk * EPB;
#pragma unroll 4
    for (int i = 0; i < EPB / 256; i++) {
        int e = base + i * 256 + tid;
        if (e < E) {
            int s = src[e];
            int key = 2 * dst[e] + et[e];
            int bk = key >> 9;
            int r = atomicAdd(&cnt[bk], 1);
            stage[basel[bk] + r] = make_uint2((uint)s, (uint)key);
        }
    }
}

// ---------------- fp32 -> bf16 conversion of x ----------------

__global__ void k_cvt(const float* __restrict__ x, uint4* __restrict__ xb, int n8) {
    int i = blockIdx.x * 256 + threadIdx.x;
    if (i >= n8) return;
    const float4 f0 = ((const float4*)x)[(size_t)i * 2];
    const float4 f1 = ((const float4*)x)[(size_t)i * 2 + 1];
    uint4 o;
    o.x = (uint)f2bf(f0.x) | ((uint)f2bf(f0.y) << 16);
    o.y = (uint)f2bf(f0.z) | ((uint)f2bf(f0.w) << 16);
    o.z = (uint)f2bf(f1.x) | ((uint)f2bf(f1.y) << 16);
    o.w = (uint)f2bf(f1.z) | ((uint)f2bf(f1.w) << 16);
    xb[i] = o;
}

// ------------- weight pre-pack into MFMA-B fragment order (bf16) -----------
// Bpk1 (gemm1, K=384 x 128 cols): 3 K-seg tiles x 2048 chunks (R5 layout).
// Bpk2 (gemmT, K=128 x 192 cols): 2 col-tiles x 2048 chunks, cols 192..255
// zero-padded (R4 layout).

__device__ __forceinline__ uint4 pack8(const ushort* o) {
    uint4 v;
    v.x = (uint)o[0] | ((uint)o[1] << 16);
    v.y = (uint)o[2] | ((uint)o[3] << 16);
    v.z = (uint)o[4] | ((uint)o[5] << 16);
    v.w = (uint)o[6] | ((uint)o[7] << 16);
    return v;
}

__global__ void k_prep(const float* __restrict__ W1root, const float* __restrict__ W1rel,
                       const float* __restrict__ W2root, const float* __restrict__ W2rel,
                       uint4* __restrict__ Bpk1, uint4* __restrict__ Bpk2) {
    int idx = blockIdx.x * 256 + threadIdx.x;
    if (idx >= 10240) return;
    ushort o[8];
    if (idx < 6144) {
        int id = idx;
        int ct = id >> 11;                 // K-segment: 0 root, 1 rel0, 2 rel1
        int c = id & 2047;
        int gn = c >> 9, s = (c >> 6) & 7, h = (c >> 5) & 1, n = c & 31;
        int k0 = s * 16 + h * 8;
        int col = gn * 32 + n;
        const float* W = (ct == 0) ? W1root : (W1rel + (size_t)(ct - 1) * 16384);
#pragma unroll
        for (int j = 0; j < 8; j++) o[j] = f2bf(W[(k0 + j) * 128 + col]);
        Bpk1[id] = pack8(o);
    } else {
        int id = idx - 6144;
        int ct = id >> 11;                 // col tile 0..1 over 256 padded cols
        int c = id & 2047;
        int gn = c >> 9, s = (c >> 6) & 7, h = (c >> 5) & 1, n = c & 31;
        int k0 = s * 16 + h * 8;
        int colg = ct * 128 + gn * 32 + n;
#pragma unroll
        for (int j = 0; j < 8; j++) {
            float f = 0.f;
            if (colg < 64)       f = W2root[(k0 + j) * 64 + colg];
            else if (colg < 128) f = W2rel[(k0 + j) * 64 + (colg - 64)];
            else if (colg < 192) f = W2rel[8192 + (k0 + j) * 64 + (colg - 128)];
            o[j] = f2bf(f);
        }
        Bpk2[id] = pack8(o);
    }
}

// ------- fused: 512-key bucket fine-sort (LDS) + gather-mean(xb) -> S1 -----
// One block (256 thr, 4 waves) per bucket (256 nodes). Emits esrc/offs for
// k_final. Gather: 8 edges in flight per round (R4 k_mid shape).

__global__ __launch_bounds__(256)
void k_agg1(const uint2* __restrict__ stage, const int* __restrict__ basebb,
            const uint* __restrict__ xb, ushort* __restrict__ S,
            int* __restrict__ esrc, int* __restrict__ offs,
            int E, int N, int NBK, int NBLK) {
    __shared__ int srcs[SRCCAP];
    __shared__ int kcnt[KPB];
    __shared__ int kends[KPB];
    __shared__ int ssum[256];
    int tid = threadIdx.x, b = blockIdx.x;
    int start = basebb[b * NBLK];
    int bend = (b == NBK - 1) ? E : basebb[(b + 1) * NBLK];
    int size = bend - start;

    kcnt[tid] = 0;
    kcnt[tid + 256] = 0;
    __syncthreads();
    for (int i = tid; i < size; i += 256) {
        uint2 p = stage[start + i];
        atomicAdd(&kcnt[p.y & (KPB - 1)], 1);
    }
    __syncthreads();
    int v0 = kcnt[2 * tid], v1 = kcnt[2 * tid + 1];
    ssum[tid] = v0 + v1;
    __syncthreads();
    for (int ofs = 1; ofs < 256; ofs <<= 1) {
        int val = ssum[tid];
        int add = (tid >= ofs) ? ssum[tid - ofs] : 0;
        __syncthreads();
        ssum[tid] = val + add;
        __syncthreads();
    }
    int texcl = (tid == 0) ? 0 : ssum[tid - 1];
    kends[2 * tid] = texcl + v0;
    kends[2 * tid + 1] = texcl + v0 + v1;
    offs[(b << 9) + 2 * tid] = start + texcl + v0;
    offs[(b << 9) + 2 * tid + 1] = start + texcl + v0 + v1;
    kcnt[2 * tid] = texcl;                 // cursor = exclusive start
    kcnt[2 * tid + 1] = texcl + v0;
    __syncthreads();
    for (int i = tid; i < size; i += 256) {
        uint2 p = stage[start + i];
        int r = atomicAdd(&kcnt[p.y & (KPB - 1)], 1);
        if (r < SRCCAP) srcs[r] = (int)p.x;
        esrc[start + r] = (int)p.x;
    }
    __syncthreads();

    // gather: wave w handles nodes ni = w, w+4, ...; 8 edges in flight.
    int w = tid >> 6, lane = tid & 63;
    int sub = lane >> 5, cl = lane & 31;
    const uint2* F = (const uint2*)xb;     // row stride 32 uint2 (128ch bf16)
    for (int ni = w; ni < 256; ni += 4) {
        int n = (b << 8) + ni;
        if (n >= N) break;
#pragma unroll
        for (int r = 0; r < 2; r++) {
            int lk = 2 * ni + r;
            int lbeg = lk ? kends[lk - 1] : 0;
            int lend = kends[lk];
            float a0 = 0.f, a1 = 0.f, a2 = 0.f, a3 = 0.f;
            for (int eb = lbeg; eb < lend; eb += 8) {
                uint2 v[4];
#pragma unroll
                for (int j = 0; j < 4; j++) {
                    int ee = eb + 2 * j + sub;
                    int id = (ee < lend) ? (ee < SRCCAP ? srcs[ee] : esrc[start + ee])
                                         : N;              // row N = zeros
                    v[j] = F[(size_t)id * 32 + cl];
                }
#pragma unroll
                for (int j = 0; j < 4; j++) {
                    a0 += bflo(v[j].x); a1 += bfhi(v[j].x);
                    a2 += bflo(v[j].y); a3 += bfhi(v[j].y);
                }
            }
            a0 += __shfl_xor(a0, 32, 64);
            a1 += __shfl_xor(a1, 32, 64);
            a2 += __shfl_xor(a2, 32, 64);
            a3 += __shfl_xor(a3, 32, 64);
            if (sub == 0) {
                float inv = (lend > lbeg) ? 1.0f / (float)(lend - lbeg) : 0.f;
                uint2 o;
                o.x = (uint)f2bf(a0 * inv) | ((uint)f2bf(a1 * inv) << 16);
                o.y = (uint)f2bf(a2 * inv) | ((uint)f2bf(a3 * inv) << 16);
                ((uint2*)(S + (size_t)n * 256 + r * 128))[cl] = o;
            }
        }
    }
}

// ------- GEMM1: h = relu([xb | S1] @ Bpk1 + b1), K=384, 128 cols, bf16 out --

__global__ __launch_bounds__(256)
void k_gemm1(const ushort* __restrict__ xb, const ushort* __restrict__ S1,
             const ushort* __restrict__ Bpk, const float* __restrict__ b1,
             ushort* __restrict__ h, int N) {
    __shared__ ushort SH[32768];
    ushort* Alds = SH;
    ushort* Blds = SH + 16384;

    const int tid = threadIdx.x;
    const int lane = tid & 63;
    const int w = tid >> 6;
    const int wm = w >> 1, wn = w & 1;
    const int rowBase = blockIdx.x * 128;

    floatx16 acc[2][2] = {};

#pragma unroll
    for (int seg = 0; seg < 3; seg++) {
        const ushort* Ap = (seg == 0) ? xb : S1;
        const int stride = (seg == 0) ? 128 : 256;
        const int aoff = (seg == 2) ? 128 : 0;
        const uint4* Bsrc = (const uint4*)Bpk + seg * 2048;
#pragma unroll
        for (int i = 0; i < 8; i++) {
            int c = tid + i * 256;
            int m = c & 31, hh = (c >> 5) & 1, s = (c >> 6) & 7, g = c >> 9;
            int row = rowBase + g * 32 + m;
            if (row >= N) row = N - 1;
            int kc = s * 2 + hh;
            ((uint4*)Alds)[c] = *(const uint4*)(Ap + (size_t)row * stride + aoff + kc * 8);
            ((uint4*)Blds)[c] = Bsrc[c];
        }
        __syncthreads();
#pragma unroll
        for (int s = 0; s < 8; s++) {
            short8 a0 = *(const short8*)&Alds[(((wm * 2 + 0) * 8 + s) * 64 + lane) * 8];
            short8 a1 = *(const short8*)&Alds[(((wm * 2 + 1) * 8 + s) * 64 + lane) * 8];
            short8 b0 = *(const short8*)&Blds[(((wn * 2 + 0) * 8 + s) * 64 + lane) * 8];
            short8 b1f = *(const short8*)&Blds[(((wn * 2 + 1) * 8 + s) * 64 + lane) * 8];
            acc[0][0] = __builtin_amdgcn_mfma_f32_32x32x16_bf16(a0, b0, acc[0][0], 0, 0, 0);
            acc[0][1] = __builtin_amdgcn_mfma_f32_32x32x16_bf16(a0, b1f, acc[0][1], 0, 0, 0);
            acc[1][0] = __builtin_amdgcn_mfma_f32_32x32x16_bf16(a1, b0, acc[1][0], 0, 0, 0);
            acc[1][1] = __builtin_amdgcn_mfma_f32_32x32x16_bf16(a1, b1f, acc[1][1], 0, 0, 0);
        }
        __syncthreads();
    }

    ushort* Clds = SH;
    const int qr = 4 * (lane >> 5);
    const int cl = lane & 31;
    float bb[2];
#pragma unroll
    for (int nt = 0; nt < 2; nt++) bb[nt] = b1[wn * 64 + nt * 32 + cl];
#pragma unroll
    for (int mt = 0; mt < 2; mt++)
#pragma unroll
        for (int nt = 0; nt < 2; nt++) {
#pragma unroll
            for (int reg = 0; reg < 16; reg++) {
                int rl = (reg & 3) + 8 * (reg >> 2) + qr;
                float v = fmaxf(acc[mt][nt][reg] + bb[nt], 0.f);
                Clds[(wm * 64 + mt * 32 + rl) * 136 + wn * 64 + nt * 32 + cl] = f2bf(v);
            }
        }
    __syncthreads();

    int r = tid >> 1, half = tid & 1;
    int grow = rowBase + r;
    if (grow < N) {
#pragma unroll
        for (int k = 0; k < 8; k++) {
            int c0 = half * 64 + k * 8;
            uint4 v = *(const uint4*)&Clds[r * 136 + c0];
            *(uint4*)(h + (size_t)grow * 128 + c0) = v;
        }
    }
}

// ------- GEMMT: t2 = h @ [W2root|W2rel0|W2rel1], K=128, Ld=192, bf16 out ---
// (R4 k_gemm, bf16-A path.)

__global__ __launch_bounds__(256)
void k_gemmT(const ushort* __restrict__ A, const ushort* __restrict__ Bpk,
             ushort* __restrict__ Out, int N, int Ld) {
    __shared__ ushort SH[32768];
    ushort* Alds = SH;
    ushort* Blds = SH + 16384;

    const int tid = threadIdx.x;
    const int lane = tid & 63;
    const int w = tid >> 6;
    const int wm = w >> 1, wn = w & 1;
    const int rowBase = blockIdx.x * 128;
    const int ct = blockIdx.y;
    const int colBase = ct * 128;

    const uint4* Bsrc = (const uint4*)Bpk + (size_t)ct * 2048;
#pragma unroll
    for (int i = 0; i < 8; i++) {
        int c = tid + i * 256;
        ((uint4*)Blds)[c] = Bsrc[c];
    }
#pragma unroll
    for (int i = 0; i < 8; i++) {
        int c = tid + i * 256;
        int m = c & 31, h = (c >> 5) & 1, s = (c >> 6) & 7, g = c >> 9;
        int row = rowBase + g * 32 + m;
        if (row >= N) row = N - 1;
        int kc = s * 2 + h;
        ((uint4*)Alds)[c] = *(const uint4*)(A + (size_t)row * 128 + kc * 8);
    }
    __syncthreads();

    floatx16 acc[2][2] = {};
#pragma unroll
    for (int s = 0; s < 8; s++) {
        short8 a0 = *(const short8*)&Alds[(((wm * 2 + 0) * 8 + s) * 64 + lane) * 8];
        short8 a1 = *(const short8*)&Alds[(((wm * 2 + 1) * 8 + s) * 64 + lane) * 8];
        short8 b0 = *(const short8*)&Blds[(((wn * 2 + 0) * 8 + s) * 64 + lane) * 8];
        short8 b1 = *(const short8*)&Blds[(((wn * 2 + 1) * 8 + s) * 64 + lane) * 8];
        acc[0][0] = __builtin_amdgcn_mfma_f32_32x32x16_bf16(a0, b0, acc[0][0], 0, 0, 0);
        acc[0][1] = __builtin_amdgcn_mfma_f32_32x32x16_bf16(a0, b1, acc[0][1], 0, 0, 0);
        acc[1][0] = __builtin_amdgcn_mfma_f32_32x32x16_bf16(a1, b0, acc[1][0], 0, 0, 0);
        acc[1][1] = __builtin_amdgcn_mfma_f32_32x32x16_bf16(a1, b1, acc[1][1], 0, 0, 0);
    }
    __syncthreads();

    ushort* Clds = SH;
    const int qr = 4 * (lane >> 5);
    const int cl = lane & 31;
#pragma unroll
    for (int mt = 0; mt < 2; mt++)
#pragma unroll
        for (int nt = 0; nt < 2; nt++) {
#pragma unroll
            for (int reg = 0; reg < 16; reg++) {
                int rl = (reg & 3) + 8 * (reg >> 2) + qr;
                Clds[(wm * 64 + mt * 32 + rl) * 136 + wn * 64 + nt * 32 + cl] =
                    f2bf(acc[mt][nt][reg]);
            }
        }
    __syncthreads();

    int r = tid >> 1, half = tid & 1;
    int grow = rowBase + r;
    if (grow < N) {
#pragma unroll
        for (int k = 0; k < 8; k++) {
            int c0 = half * 64 + k * 8;
            int col = colBase + c0;
            if (col < Ld) {
                uint4 v = *(const uint4*)&Clds[r * 136 + c0];
                *(uint4*)(Out + (size_t)grow * Ld + col) = v;
            }
        }
    }
}

// ------- layer-2 fused: gather-mean (4 edges/round) + root + bias + L2 -----
// T2: [N x 192] bf16 rows (48 uint2): uint2 0..15 root, 16..31 rel0, 32..47 rel1.
// Zero row at id == N.

__global__ void k_final(const ushort* __restrict__ T2, const float* __restrict__ b2,
                        const int* __restrict__ offs, const int* __restrict__ esrc,
                        float* __restrict__ out, int N) {
    int wid = (int)((blockIdx.x * 256L + threadIdx.x) >> 6);
    int lane = threadIdx.x & 63;
    if (wid >= N) return;
    int q = lane >> 4, c = lane & 15;
    const uint2* Tb = (const uint2*)T2;   // row stride 48 uint2

    int end0 = offs[2 * wid], end1 = offs[2 * wid + 1];
    int beg0 = (wid == 0) ? 0 : offs[2 * wid - 1];

    float t0 = 0.f, t1 = 0.f, t2 = 0.f, t3 = 0.f;
#pragma unroll
    for (int r = 0; r < 2; r++) {
        int beg = r ? end0 : beg0;
        int end = r ? end1 : end0;
        if (end > beg) {
            float a0 = 0.f, a1 = 0.f, a2 = 0.f, a3 = 0.f;
            const uint2* Y = Tb + 16 + 16 * r + c;
            for (int eb = beg; eb < end; eb += 8) {
                uint2 v[2];
#pragma unroll
                for (int j = 0; j < 2; j++) {
                    int ee = eb + 4 * j + q;
                    int id = (ee < end) ? esrc[ee] : N;    // row N = zeros
                    v[j] = Y[(size_t)id * 48];
                }
#pragma unroll
                for (int j = 0; j < 2; j++) {
                    a0 += bflo(v[j].x); a1 += bfhi(v[j].x);
                    a2 += bflo(v[j].y); a3 += bfhi(v[j].y);
                }
            }
            float inv = 1.0f / (float)(end - beg);
            t0 += a0 * inv; t1 += a1 * inv; t2 += a2 * inv; t3 += a3 * inv;
        }
    }
#pragma unroll
    for (int d = 16; d <= 32; d <<= 1) {
        t0 += __shfl_xor(t0, d, 64);
        t1 += __shfl_xor(t1, d, 64);
        t2 += __shfl_xor(t2, d, 64);
        t3 += __shfl_xor(t3, d, 64);
    }
    uint2 ru = Tb[(size_t)wid * 48 + c];
    float4 bb = *(const float4*)(b2 + 4 * c);
    float v0 = bflo(ru.x) + bb.x + t0;
    float v1 = bfhi(ru.x) + bb.y + t1;
    float v2 = bflo(ru.y) + bb.z + t2;
    float v3 = bfhi(ru.y) + bb.w + t3;
    float sq = v0 * v0 + v1 * v1 + v2 * v2 + v3 * v3;
#pragma unroll
    for (int d = 1; d <= 8; d <<= 1) sq += __shfl_xor(sq, d, 64);
    float rn = 1.0f / fmaxf(sqrtf(sq), 1e-12f);
    if (lane < 16) {
        float4 o = {v0 * rn, v1 * rn, v2 * rn, v3 * rn};
        *(float4*)(out + (size_t)wid * 64 + 4 * c) = o;
    }
}

// ---------------- launch ----------------

extern "C" void kernel_launch(void* const* d_in, const int* in_sizes, int n_in,
                              void* d_out, int out_size, void* d_ws, size_t ws_size,
                              hipStream_t stream) {
    const float* x      = (const float*)d_in[0];
    const int*   ei     = (const int*)d_in[1];
    const int*   etype  = (const int*)d_in[2];
    const float* W1rel  = (const float*)d_in[3];
    const float* W1root = (const float*)d_in[4];
    const float* b1     = (const float*)d_in[5];
    const float* W2rel  = (const float*)d_in[6];
    const float* W2root = (const float*)d_in[7];
    const float* b2     = (const float*)d_in[8];
    float* out = (float*)d_out;

    const int N = in_sizes[0] / IN_CH;   // 100000
    const int E = in_sizes[2];           // 1600000
    const int NKEY = 2 * N;
    const int NBK  = (NKEY + KPB - 1) / KPB;   // 391 buckets
    const int NBLK = (E + EPB - 1) / EPB;      // 196 partition blocks
    const int NSC  = NBK * NBLK;

    const int* src = ei;
    const int* dst = ei + E;

    char* base = (char*)d_ws;
    size_t off = 0;
    auto carve = [&](size_t bytes) -> void* {
        void* p = base + off;
        off = (off + bytes + 511) & ~(size_t)511;
        return p;
    };
    ushort* xb    = (ushort*)carve((size_t)(N + 1) * 128 * sizeof(ushort)); // +zero row
    ushort* hA    = (ushort*)carve((size_t)N * 128 * sizeof(ushort));
    ushort* S1    = (ushort*)carve((size_t)N * 256 * sizeof(ushort));       // 51.2MB
    ushort* t2    = (ushort*)carve((size_t)(N + 1) * 192 * sizeof(ushort)); // +zero row
    int*    esrc  = (int*)carve((size_t)E * sizeof(int));
    uint2*  stage = (uint2*)carve((size_t)E * sizeof(uint2));
    int*    offs  = (int*)carve((size_t)NBK * KPB * sizeof(int));
    int*    cntblk= (int*)carve((size_t)NSC * sizeof(int));
    int*    basebb= (int*)carve((size_t)(NSC + 1) * sizeof(int));
    int     NB    = (NSC + SCAN_CHUNK - 1) / SCAN_CHUNK;
    int*    bsums = (int*)carve((size_t)NB * sizeof(int));
    uint4*  Bpk1  = (uint4*)carve(6144 * sizeof(uint4));
    uint4*  Bpk2  = (uint4*)carve(4096 * sizeof(uint4));
    (void)ws_size; (void)n_in; (void)out_size;

    // zero rows (id==N in gathers)
    hipMemsetAsync(xb + (size_t)N * 128, 0, 128 * sizeof(ushort), stream);
    hipMemsetAsync(t2 + (size_t)N * 192, 0, 192 * sizeof(ushort), stream);

    // radix partition
    k_count<<<NBLK, 256, 0, stream>>>(dst, etype, cntblk, E, NBK, NBLK);
    k_scan_a<<<NB, 256, 0, stream>>>(cntblk, basebb, bsums, NSC);
    k_scan_b<<<1, 64, 0, stream>>>(bsums, basebb, NB, NSC);
    k_scan_c<<<(NSC + 255) / 256, 256, 0, stream>>>(basebb, bsums, NSC);
    k_part<<<NBLK, 256, 0, stream>>>(src, dst, etype, basebb, stage, E, NBK, NBLK);

    int n8 = N * 16;
    k_cvt<<<(n8 + 255) / 256, 256, 0, stream>>>(x, (uint4*)xb, n8);
    k_prep<<<40, 256, 0, stream>>>(W1root, W1rel, W2root, W2rel, Bpk1, Bpk2);

    int rowTiles = (N + 127) / 128;
    int nodeBlocks = (int)(((long long)N * 64 + 255) / 256);

    // Layer 1: S1 = seg-mean(xb), h = relu([xb|S1] @ W1 + b1)
    k_agg1<<<NBK, 256, 0, stream>>>(stage, basebb, (const uint*)xb, S1,
                                    esrc, offs, E, N, NBK, NBLK);
    k_gemm1<<<rowTiles, 256, 0, stream>>>(xb, S1, (const ushort*)Bpk1, b1, hA, N);

    // Layer 2: t2 = h @ [W2root|W2rel0|W2rel1], fused gather+L2norm
    k_gemmT<<<dim3(rowTiles, 2), 256, 0, stream>>>(hA, (const ushort*)Bpk2, t2, N, 192);
    k_final<<<nodeBlocks, 256, 0, stream>>>(t2, b2, offs, esrc, out, N);
}

// Round 8
// 373.283 us; speedup vs baseline: 1.5961x; 1.5961x over previous
//
#include <hip/hip_runtime.h>
#include <hip/hip_bf16.h>

// RGCN: 2-layer relational GCN + L2 normalize.
// R7: sort decoupled from gather. k_fine (391 blocks) builds esrc/offs;
//     k_agg/k_final are node-parallel (wave/node, zero LDS, 8 waves/SIMD)
//     with shfl-broadcast edge indices. L1 aggregate-first (gather xb),
//     L2 transform-first (gather t2 at 128B/edge). 4-byte packed stage.

typedef unsigned int uint;
typedef unsigned short ushort;
typedef __attribute__((ext_vector_type(8))) short short8;
typedef __attribute__((ext_vector_type(16))) float floatx16;

#define IN_CH  128
#define OUT_CH 64
#define SCAN_CHUNK 2048
#define EPB 8192          // edges per partition block
#define KPB 512           // keys per bucket (256 nodes x 2 rels)
#define MAXBK 400         // bucket counters (NBK=391)

__device__ __forceinline__ ushort f2bf(float f) {
    uint u = __float_as_uint(f);
    u += 0x7FFF + ((u >> 16) & 1);
    return (ushort)(u >> 16);
}
__device__ __forceinline__ float bflo(uint u) { return __uint_as_float(u << 16); }
__device__ __forceinline__ float bfhi(uint u) { return __uint_as_float(u & 0xFFFF0000u); }

// ---------------- radix partition: key = 2*dst + et, bucket = key>>9 -------

__global__ void k_count(const int* __restrict__ dst, const int* __restrict__ et,
                        int* __restrict__ cntblk, int E, int NBK, int NBLK) {
    __shared__ int cnt[MAXBK];
    int tid = threadIdx.x, blk = blockIdx.x;
    for (int b = tid; b < NBK; b += 256) cnt[b] = 0;
    __syncthreads();
    int base = blk * EPB;
#pragma unroll 4
    for (int i = 0; i < EPB / 256; i++) {
        int e = base + i * 256 + tid;
        if (e < E) {
            int key = 2 * dst[e] + et[e];
            atomicAdd(&cnt[key >> 9], 1);
        }
    }
    __syncthreads();
    for (int b = tid; b < NBK; b += 256) cntblk[b * NBLK + blk] = cnt[b];
}

__global__ void k_scan_a(const int* __restrict__ deg, int* __restrict__ offs,
                         int* __restrict__ bsums, int n) {
    __shared__ int sdata[256];
    int b = blockIdx.x, t = threadIdx.x;
    int base = b * SCAN_CHUNK + t * 8;
    int v[8];
    int sum = 0;
#pragma unroll
    for (int i = 0; i < 8; i++) {
        int idx = base + i;
        int x = (idx < n) ? deg[idx] : 0;
        v[i] = sum;
        sum += x;
    }
    sdata[t] = sum;
    __syncthreads();
    for (int ofs = 1; ofs < 256; ofs <<= 1) {
        int val = sdata[t];
        int add = (t >= ofs) ? sdata[t - ofs] : 0;
        __syncthreads();
        sdata[t] = val + add;
        __syncthreads();
    }
    int texcl = (t == 0) ? 0 : sdata[t - 1];
    if (t == 255) bsums[b] = sdata[255];
#pragma unroll
    for (int i = 0; i < 8; i++) {
        int idx = base + i;
        if (idx < n) offs[idx] = texcl + v[i];
    }
}

__global__ void k_scan_b(int* __restrict__ bsums, int* __restrict__ offs, int nb, int n) {
    if (blockIdx.x == 0 && threadIdx.x == 0) {
        int run = 0;
        for (int b = 0; b < nb; b++) {
            int t = bsums[b];
            bsums[b] = run;
            run += t;
        }
        offs[n] = run;
    }
}

__global__ void k_scan_c(int* __restrict__ offs, const int* __restrict__ bsums, int n) {
    int i = blockIdx.x * blockDim.x + threadIdx.x;
    if (i < n) offs[i] += bsums[i / SCAN_CHUNK];
}

// stage entry: (key & 511) << 23 | src   (src < 2^23)
__global__ void k_part(const int* __restrict__ src, const int* __restrict__ dst,
                       const int* __restrict__ et, const int* __restrict__ basebb,
                       uint* __restrict__ stage, int E, int NBK, int NBLK) {
    __shared__ int cnt[MAXBK];
    __shared__ int basel[MAXBK];
    int tid = threadIdx.x, blk = blockIdx.x;
    for (int b = tid; b < NBK; b += 256) {
        cnt[b] = 0;
        basel[b] = basebb[b * NBLK + blk];
    }
    __syncthreads();
    int base = blk * EPB;
#pragma unroll 4
    for (int i = 0; i < EPB / 256; i++) {
        int e = base + i * 256 + tid;
        if (e < E) {
            int s = src[e];
            int key = 2 * dst[e] + et[e];
            int bk = key >> 9;
            int r = atomicAdd(&cnt[bk], 1);
            stage[basel[bk] + r] = ((uint)(key & 511) << 23) | (uint)s;
        }
    }
}

// fine sort within 512-key bucket -> offs (global ends) + esrc.
__global__ void k_fine(const uint* __restrict__ stage, const int* __restrict__ basebb,
                       int* __restrict__ offs, int* __restrict__ esrc,
                       int E, int NBK, int NBLK) {
    __shared__ int kcnt[KPB];
    __shared__ int kcur[KPB];
    __shared__ int ssum[256];
    int tid = threadIdx.x, b = blockIdx.x;
    int start = basebb[b * NBLK];
    int endB = (b == NBK - 1) ? E : basebb[(b + 1) * NBLK];
    int size = endB - start;

    kcnt[tid] = 0;
    kcnt[tid + 256] = 0;
    __syncthreads();
    for (int i = tid; i < size; i += 256)
        atomicAdd(&kcnt[stage[start + i] >> 23], 1);
    __syncthreads();
    int v0 = kcnt[2 * tid], v1 = kcnt[2 * tid + 1];
    ssum[tid] = v0 + v1;
    __syncthreads();
    for (int ofs = 1; ofs < 256; ofs <<= 1) {
        int val = ssum[tid];
        int add = (tid >= ofs) ? ssum[tid - ofs] : 0;
        __syncthreads();
        ssum[tid] = val + add;
        __syncthreads();
    }
    int texcl = (tid == 0) ? 0 : ssum[tid - 1];
    kcur[2 * tid] = texcl;
    kcur[2 * tid + 1] = texcl + v0;
    offs[(b << 9) + 2 * tid] = start + texcl + v0;
    offs[(b << 9) + 2 * tid + 1] = start + texcl + v0 + v1;
    __syncthreads();
    for (int i = tid; i < size; i += 256) {
        uint p = stage[start + i];
        int r = atomicAdd(&kcur[p >> 23], 1);
        esrc[start + r] = (int)(p & 0x7FFFFFu);
    }
}

// ---------------- fp32 -> bf16 conversion of x ----------------

__global__ void k_cvt(const float* __restrict__ x, uint4* __restrict__ xb, int n8) {
    int i = blockIdx.x * 256 + threadIdx.x;
    if (i >= n8) return;
    const float4 f0 = ((const float4*)x)[(size_t)i * 2];
    const float4 f1 = ((const float4*)x)[(size_t)i * 2 + 1];
    uint4 o;
    o.x = (uint)f2bf(f0.x) | ((uint)f2bf(f0.y) << 16);
    o.y = (uint)f2bf(f0.z) | ((uint)f2bf(f0.w) << 16);
    o.z = (uint)f2bf(f1.x) | ((uint)f2bf(f1.y) << 16);
    o.w = (uint)f2bf(f1.z) | ((uint)f2bf(f1.w) << 16);
    xb[i] = o;
}

// ------------- weight pre-pack into MFMA-B fragment order (bf16) -----------

__device__ __forceinline__ uint4 pack8(const ushort* o) {
    uint4 v;
    v.x = (uint)o[0] | ((uint)o[1] << 16);
    v.y = (uint)o[2] | ((uint)o[3] << 16);
    v.z = (uint)o[4] | ((uint)o[5] << 16);
    v.w = (uint)o[6] | ((uint)o[7] << 16);
    return v;
}

__global__ void k_prep(const float* __restrict__ W1root, const float* __restrict__ W1rel,
                       const float* __restrict__ W2root, const float* __restrict__ W2rel,
                       uint4* __restrict__ Bpk1, uint4* __restrict__ Bpk2) {
    int idx = blockIdx.x * 256 + threadIdx.x;
    if (idx >= 10240) return;
    ushort o[8];
    if (idx < 6144) {
        int id = idx;
        int ct = id >> 11;                 // K-segment: 0 root, 1 rel0, 2 rel1
        int c = id & 2047;
        int gn = c >> 9, s = (c >> 6) & 7, h = (c >> 5) & 1, n = c & 31;
        int k0 = s * 16 + h * 8;
        int col = gn * 32 + n;
        const float* W = (ct == 0) ? W1root : (W1rel + (size_t)(ct - 1) * 16384);
#pragma unroll
        for (int j = 0; j < 8; j++) o[j] = f2bf(W[(k0 + j) * 128 + col]);
        Bpk1[id] = pack8(o);
    } else {
        int id = idx - 6144;
        int ct = id >> 11;                 // col tile 0..1 over 256 padded cols
        int c = id & 2047;
        int gn = c >> 9, s = (c >> 6) & 7, h = (c >> 5) & 1, n = c & 31;
        int k0 = s * 16 + h * 8;
        int colg = ct * 128 + gn * 32 + n;
#pragma unroll
        for (int j = 0; j < 8; j++) {
            float f = 0.f;
            if (colg < 64)       f = W2root[(k0 + j) * 64 + colg];
            else if (colg < 128) f = W2rel[(k0 + j) * 64 + (colg - 64)];
            else if (colg < 192) f = W2rel[8192 + (k0 + j) * 64 + (colg - 128)];
            o[j] = f2bf(f);
        }
        Bpk2[id] = pack8(o);
    }
}

// ------- layer-1 gather: wave per node, mean(xb[src]) per rel -> S1 --------
// Edge ids preloaded per 64-chunk into a register and shfl-broadcast.
// Lanes beyond segment end hold id=N (zero row) -> padding is free.

__global__ __launch_bounds__(256)
void k_agg(const int* __restrict__ offs, const int* __restrict__ esrc,
           const uint* __restrict__ xb, uint2* __restrict__ S, int N) {
    int wid = (int)((blockIdx.x * 256L + threadIdx.x) >> 6);
    int lane = threadIdx.x & 63;
    if (wid >= N) return;
    int sub = lane >> 5, cl = lane & 31;
    const uint2* F = (const uint2*)xb;     // row stride 32 uint2 (128ch bf16)

    int beg0 = (wid == 0) ? 0 : offs[2 * wid - 1];
    int end0 = offs[2 * wid], end1 = offs[2 * wid + 1];

    uint2 o = make_uint2(0, 0);
#pragma unroll
    for (int r = 0; r < 2; r++) {
        int beg = r ? end0 : beg0;
        int end = r ? end1 : end0;
        float a0 = 0.f, a1 = 0.f, a2 = 0.f, a3 = 0.f;
        for (int c0 = beg; c0 < end; c0 += 64) {
            int myid = (c0 + lane < end) ? esrc[c0 + lane] : N;
            int m = min(64, end - c0);
            for (int eb = 0; eb < m; eb += 8) {
                uint2 v[4];
#pragma unroll
                for (int j = 0; j < 4; j++) {
                    int id = __shfl(myid, eb + 2 * j + sub, 64);
                    v[j] = F[(size_t)id * 32 + cl];
                }
#pragma unroll
                for (int j = 0; j < 4; j++) {
                    a0 += bflo(v[j].x); a1 += bfhi(v[j].x);
                    a2 += bflo(v[j].y); a3 += bfhi(v[j].y);
                }
            }
        }
        a0 += __shfl_xor(a0, 32, 64);
        a1 += __shfl_xor(a1, 32, 64);
        a2 += __shfl_xor(a2, 32, 64);
        a3 += __shfl_xor(a3, 32, 64);
        if (sub == r) {
            float inv = (end > beg) ? 1.0f / (float)(end - beg) : 0.f;
            o.x = (uint)f2bf(a0 * inv) | ((uint)f2bf(a1 * inv) << 16);
            o.y = (uint)f2bf(a2 * inv) | ((uint)f2bf(a3 * inv) << 16);
        }
    }
    // S row = [rel0 128ch | rel1 128ch] = 64 uint2; lane = sub*32+cl.
    S[(size_t)wid * 64 + lane] = o;
}

// ------- GEMM1: h = relu([xb | S1] @ Bpk1 + b1), K=384, 128 cols, bf16 out --

__global__ __launch_bounds__(256)
void k_gemm1(const ushort* __restrict__ xb, const ushort* __restrict__ S1,
             const ushort* __restrict__ Bpk, const float* __restrict__ b1,
             ushort* __restrict__ h, int N) {
    __shared__ ushort SH[32768];
    ushort* Alds = SH;
    ushort* Blds = SH + 16384;

    const int tid = threadIdx.x;
    const int lane = tid & 63;
    const int w = tid >> 6;
    const int wm = w >> 1, wn = w & 1;
    const int rowBase = blockIdx.x * 128;

    floatx16 acc[2][2] = {};

#pragma unroll
    for (int seg = 0; seg < 3; seg++) {
        const ushort* Ap = (seg == 0) ? xb : S1;
        const int stride = (seg == 0) ? 128 : 256;
        const int aoff = (seg == 2) ? 128 : 0;
        const uint4* Bsrc = (const uint4*)Bpk + seg * 2048;
#pragma unroll
        for (int i = 0; i < 8; i++) {
            int c = tid + i * 256;
            int m = c & 31, hh = (c >> 5) & 1, s = (c >> 6) & 7, g = c >> 9;
            int row = rowBase + g * 32 + m;
            if (row >= N) row = N - 1;
            int kc = s * 2 + hh;
            ((uint4*)Alds)[c] = *(const uint4*)(Ap + (size_t)row * stride + aoff + kc * 8);
            ((uint4*)Blds)[c] = Bsrc[c];
        }
        __syncthreads();
#pragma unroll
        for (int s = 0; s < 8; s++) {
            short8 a0 = *(const short8*)&Alds[(((wm * 2 + 0) * 8 + s) * 64 + lane) * 8];
            short8 a1 = *(const short8*)&Alds[(((wm * 2 + 1) * 8 + s) * 64 + lane) * 8];
            short8 b0 = *(const short8*)&Blds[(((wn * 2 + 0) * 8 + s) * 64 + lane) * 8];
            short8 b1f = *(const short8*)&Blds[(((wn * 2 + 1) * 8 + s) * 64 + lane) * 8];
            acc[0][0] = __builtin_amdgcn_mfma_f32_32x32x16_bf16(a0, b0, acc[0][0], 0, 0, 0);
            acc[0][1] = __builtin_amdgcn_mfma_f32_32x32x16_bf16(a0, b1f, acc[0][1], 0, 0, 0);
            acc[1][0] = __builtin_amdgcn_mfma_f32_32x32x16_bf16(a1, b0, acc[1][0], 0, 0, 0);
            acc[1][1] = __builtin_amdgcn_mfma_f32_32x32x16_bf16(a1, b1f, acc[1][1], 0, 0, 0);
        }
        __syncthreads();
    }

    ushort* Clds = SH;
    const int qr = 4 * (lane >> 5);
    const int cl = lane & 31;
    float bb[2];
#pragma unroll
    for (int nt = 0; nt < 2; nt++) bb[nt] = b1[wn * 64 + nt * 32 + cl];
#pragma unroll
    for (int mt = 0; mt < 2; mt++)
#pragma unroll
        for (int nt = 0; nt < 2; nt++) {
#pragma unroll
            for (int reg = 0; reg < 16; reg++) {
                int rl = (reg & 3) + 8 * (reg >> 2) + qr;
                float v = fmaxf(acc[mt][nt][reg] + bb[nt], 0.f);
                Clds[(wm * 64 + mt * 32 + rl) * 136 + wn * 64 + nt * 32 + cl] = f2bf(v);
            }
        }
    __syncthreads();

    int r = tid >> 1, half = tid & 1;
    int grow = rowBase + r;
    if (grow < N) {
#pragma unroll
        for (int k = 0; k < 8; k++) {
            int c0 = half * 64 + k * 8;
            uint4 v = *(const uint4*)&Clds[r * 136 + c0];
            *(uint4*)(h + (size_t)grow * 128 + c0) = v;
        }
    }
}

// ------- GEMMT: t2 = h @ [W2root|W2rel0|W2rel1], K=128, Ld=192, bf16 out ---

__global__ __launch_bounds__(256)
void k_gemmT(const ushort* __restrict__ A, const ushort* __restrict__ Bpk,
             ushort* __restrict__ Out, int N, int Ld) {
    __shared__ ushort SH[32768];
    ushort* Alds = SH;
    ushort* Blds = SH + 16384;

    const int tid = threadIdx.x;
    const int lane = tid & 63;
    const int w = tid >> 6;
    const int wm = w >> 1, wn = w & 1;
    const int rowBase = blockIdx.x * 128;
    const int ct = blockIdx.y;
    const int colBase = ct * 128;

    const uint4* Bsrc = (const uint4*)Bpk + (size_t)ct * 2048;
#pragma unroll
    for (int i = 0; i < 8; i++) {
        int c = tid + i * 256;
        ((uint4*)Blds)[c] = Bsrc[c];
    }
#pragma unroll
    for (int i = 0; i < 8; i++) {
        int c = tid + i * 256;
        int m = c & 31, h = (c >> 5) & 1, s = (c >> 6) & 7, g = c >> 9;
        int row = rowBase + g * 32 + m;
        if (row >= N) row = N - 1;
        int kc = s * 2 + h;
        ((uint4*)Alds)[c] = *(const uint4*)(A + (size_t)row * 128 + kc * 8);
    }
    __syncthreads();

    floatx16 acc[2][2] = {};
#pragma unroll
    for (int s = 0; s < 8; s++) {
        short8 a0 = *(const short8*)&Alds[(((wm * 2 + 0) * 8 + s) * 64 + lane) * 8];
        short8 a1 = *(const short8*)&Alds[(((wm * 2 + 1) * 8 + s) * 64 + lane) * 8];
        short8 b0 = *(const short8*)&Blds[(((wn * 2 + 0) * 8 + s) * 64 + lane) * 8];
        short8 b1 = *(const short8*)&Blds[(((wn * 2 + 1) * 8 + s) * 64 + lane) * 8];
        acc[0][0] = __builtin_amdgcn_mfma_f32_32x32x16_bf16(a0, b0, acc[0][0], 0, 0, 0);
        acc[0][1] = __builtin_amdgcn_mfma_f32_32x32x16_bf16(a0, b1, acc[0][1], 0, 0, 0);
        acc[1][0] = __builtin_amdgcn_mfma_f32_32x32x16_bf16(a1, b0, acc[1][0], 0, 0, 0);
        acc[1][1] = __builtin_amdgcn_mfma_f32_32x32x16_bf16(a1, b1, acc[1][1], 0, 0, 0);
    }
    __syncthreads();

    ushort* Clds = SH;
    const int qr = 4 * (lane >> 5);
    const int cl = lane & 31;
#pragma unroll
    for (int mt = 0; mt < 2; mt++)
#pragma unroll
        for (int nt = 0; nt < 2; nt++) {
#pragma unroll
            for (int reg = 0; reg < 16; reg++) {
                int rl = (reg & 3) + 8 * (reg >> 2) + qr;
                Clds[(wm * 64 + mt * 32 + rl) * 136 + wn * 64 + nt * 32 + cl] =
                    f2bf(acc[mt][nt][reg]);
            }
        }
    __syncthreads();

    int r = tid >> 1, half = tid & 1;
    int grow = rowBase + r;
    if (grow < N) {
#pragma unroll
        for (int k = 0; k < 8; k++) {
            int c0 = half * 64 + k * 8;
            int col = colBase + c0;
            if (col < Ld) {
                uint4 v = *(const uint4*)&Clds[r * 136 + c0];
                *(uint4*)(Out + (size_t)grow * Ld + col) = v;
            }
        }
    }
}

// ------- layer-2 fused: gather-mean of t2 + root + bias + L2 norm ----------
// T2: [N+1 x 192] bf16 rows (48 uint2); uint2 0..15 root, 16..31 rel0,
// 32..47 rel1; row N = zeros. Wave per node; shfl-broadcast edge ids.

__global__ __launch_bounds__(256)
void k_final(const ushort* __restrict__ T2, const float* __restrict__ b2,
             const int* __restrict__ offs, const int* __restrict__ esrc,
             float* __restrict__ out, int N) {
    int wid = (int)((blockIdx.x * 256L + threadIdx.x) >> 6);
    int lane = threadIdx.x & 63;
    if (wid >= N) return;
    int q = lane >> 4, c = lane & 15;
    const uint2* Tb = (const uint2*)T2;   // row stride 48 uint2

    int beg0 = (wid == 0) ? 0 : offs[2 * wid - 1];
    int end0 = offs[2 * wid], end1 = offs[2 * wid + 1];

    float t0 = 0.f, t1 = 0.f, t2 = 0.f, t3 = 0.f;
#pragma unroll
    for (int r = 0; r < 2; r++) {
        int beg = r ? end0 : beg0;
        int end = r ? end1 : end0;
        if (end > beg) {
            float a0 = 0.f, a1 = 0.f, a2 = 0.f, a3 = 0.f;
            const uint2* Y = Tb + 16 + 16 * r + c;
            for (int c0 = beg; c0 < end; c0 += 64) {
                int myid = (c0 + lane < end) ? esrc[c0 + lane] : N;
                int m = min(64, end - c0);
                for (int eb = 0; eb < m; eb += 8) {
                    uint2 v[2];
#pragma unroll
                    for (int j = 0; j < 2; j++) {
                        int id = __shfl(myid, eb + 4 * j + q, 64);
                        v[j] = Y[(size_t)id * 48];
                    }
#pragma unroll
                    for (int j = 0; j < 2; j++) {
                        a0 += bflo(v[j].x); a1 += bfhi(v[j].x);
                        a2 += bflo(v[j].y); a3 += bfhi(v[j].y);
                    }
                }
            }
            float inv = 1.0f / (float)(end - beg);
            t0 += a0 * inv; t1 += a1 * inv; t2 += a2 * inv; t3 += a3 * inv;
        }
    }
#pragma unroll
    for (int d = 16; d <= 32; d <<= 1) {
        t0 += __shfl_xor(t0, d, 64);
        t1 += __shfl_xor(t1, d, 64);
        t2 += __shfl_xor(t2, d, 64);
        t3 += __shfl_xor(t3, d, 64);
    }
    uint2 ru = Tb[(size_t)wid * 48 + c];
    float4 bb = *(const float4*)(b2 + 4 * c);
    float v0 = bflo(ru.x) + bb.x + t0;
    float v1 = bfhi(ru.x) + bb.y + t1;
    float v2 = bflo(ru.y) + bb.z + t2;
    float v3 = bfhi(ru.y) + bb.w + t3;
    float sq = v0 * v0 + v1 * v1 + v2 * v2 + v3 * v3;
#pragma unroll
    for (int d = 1; d <= 8; d <<= 1) sq += __shfl_xor(sq, d, 64);
    float rn = 1.0f / fmaxf(sqrtf(sq), 1e-12f);
    if (lane < 16) {
        float4 o = {v0 * rn, v1 * rn, v2 * rn, v3 * rn};
        *(float4*)(out + (size_t)wid * 64 + 4 * c) = o;
    }
}

// ---------------- launch ----------------

extern "C" void kernel_launch(void* const* d_in, const int* in_sizes, int n_in,
                              void* d_out, int out_size, void* d_ws, size_t ws_size,
                              hipStream_t stream) {
    const float* x      = (const float*)d_in[0];
    const int*   ei     = (const int*)d_in[1];
    const int*   etype  = (const int*)d_in[2];
    const float* W1rel  = (const float*)d_in[3];
    const float* W1root = (const float*)d_in[4];
    const float* b1     = (const float*)d_in[5];
    const float* W2rel  = (const float*)d_in[6];
    const float* W2root = (const float*)d_in[7];
    const float* b2     = (const float*)d_in[8];
    float* out = (float*)d_out;

    const int N = in_sizes[0] / IN_CH;   // 100000
    const int E = in_sizes[2];           // 1600000
    const int NKEY = 2 * N;
    const int NBK  = (NKEY + KPB - 1) / KPB;   // 391 buckets
    const int NBLK = (E + EPB - 1) / EPB;      // 196 partition blocks
    const int NSC  = NBK * NBLK;

    const int* src = ei;
    const int* dst = ei + E;

    char* base = (char*)d_ws;
    size_t off = 0;
    auto carve = [&](size_t bytes) -> void* {
        void* p = base + off;
        off = (off + bytes + 511) & ~(size_t)511;
        return p;
    };
    ushort* xb    = (ushort*)carve((size_t)(N + 1) * 128 * sizeof(ushort)); // +zero row
    ushort* hA    = (ushort*)carve((size_t)N * 128 * sizeof(ushort));
    ushort* S1    = (ushort*)carve((size_t)N * 256 * sizeof(ushort));       // 51.2MB
    ushort* t2    = (ushort*)carve((size_t)(N + 1) * 192 * sizeof(ushort)); // +zero row
    int*    esrc  = (int*)carve((size_t)E * sizeof(int));
    uint*   stage = (uint*)carve((size_t)E * sizeof(uint));                 // 6.4MB
    int*    offs  = (int*)carve((size_t)NBK * KPB * sizeof(int));
    int*    cntblk= (int*)carve((size_t)NSC * sizeof(int));
    int*    basebb= (int*)carve((size_t)(NSC + 1) * sizeof(int));
    int     NB    = (NSC + SCAN_CHUNK - 1) / SCAN_CHUNK;
    int*    bsums = (int*)carve((size_t)NB * sizeof(int));
    uint4*  Bpk1  = (uint4*)carve(6144 * sizeof(uint4));
    uint4*  Bpk2  = (uint4*)carve(4096 * sizeof(uint4));
    (void)ws_size; (void)n_in; (void)out_size;

    // zero rows (id==N in gathers)
    hipMemsetAsync(xb + (size_t)N * 128, 0, 128 * sizeof(ushort), stream);
    hipMemsetAsync(t2 + (size_t)N * 192, 0, 192 * sizeof(ushort), stream);

    // radix partition + fine sort
    k_count<<<NBLK, 256, 0, stream>>>(dst, etype, cntblk, E, NBK, NBLK);
    k_scan_a<<<NB, 256, 0, stream>>>(cntblk, basebb, bsums, NSC);
    k_scan_b<<<1, 64, 0, stream>>>(bsums, basebb, NB, NSC);
    k_scan_c<<<(NSC + 255) / 256, 256, 0, stream>>>(basebb, bsums, NSC);
    k_part<<<NBLK, 256, 0, stream>>>(src, dst, etype, basebb, stage, E, NBK, NBLK);
    k_fine<<<NBK, 256, 0, stream>>>(stage, basebb, offs, esrc, E, NBK, NBLK);

    int n8 = N * 16;
    k_cvt<<<(n8 + 255) / 256, 256, 0, stream>>>(x, (uint4*)xb, n8);
    k_prep<<<40, 256, 0, stream>>>(W1root, W1rel, W2root, W2rel, Bpk1, Bpk2);

    int rowTiles = (N + 127) / 128;
    int nodeBlocks = (int)(((long long)N * 64 + 255) / 256);

    // Layer 1: S1 = seg-mean(xb), h = relu([xb|S1] @ W1 + b1)
    k_agg<<<nodeBlocks, 256, 0, stream>>>(offs, esrc, (const uint*)xb, (uint2*)S1, N);
    k_gemm1<<<rowTiles, 256, 0, stream>>>(xb, S1, (const ushort*)Bpk1, b1, hA, N);

    // Layer 2: t2 = h @ [W2root|W2rel0|W2rel1], fused gather+L2norm
    k_gemmT<<<dim3(rowTiles, 2), 256, 0, stream>>>(hA, (const ushort*)Bpk2, t2, N, 192);
    k_final<<<nodeBlocks, 256, 0, stream>>>(t2, b2, offs, esrc, out, N);
}